// Round 3
// baseline (12729.189 us; speedup 1.0000x reference)
//
#include <hip/hip_runtime.h>
#include <hip/hip_bf16.h>

// Seq2seq GRU (2-layer enc T=192, 2-layer dec T=96), B=128, H=1024.
// Round 2: persistent kernel for all 290 diagonal steps with an internal
// device-wide software barrier (no per-step kernel launches). Per step,
// 1024 tile-tasks (16x16 x 3 gates), each done by a 2-wave team with
// K-split-2 + LDS reduction -> ~2048 active waves/step for latency hiding.
// bf16 MFMA (fp32 accum), fp32 master hidden state, fp32 projection.

#define H 1024
#define G 3072   /* 3*H */
#define BB 128
#define TENC 192
#define TDEC 96
#define NBLK 224
#define NSTEP 290   /* 193 enc + 97 dec diagonal steps */

typedef __attribute__((ext_vector_type(4))) float f32x4;
typedef __attribute__((ext_vector_type(8))) short bf16x8;

__device__ __forceinline__ float sigmoidf_(float x) {
    return 1.0f / (1.0f + __expf(-x));
}

__device__ __forceinline__ short f2bf_rne(float f) {
    union { float f; unsigned u; } v; v.f = f;
    unsigned r = v.u + 0x7fffu + ((v.u >> 16) & 1u);
    return (short)(r >> 16);
}

__global__ __launch_bounds__(256) void k_f2bf(const float* __restrict__ in,
                                              short* __restrict__ out, int n) {
    for (int i = blockIdx.x * 256 + threadIdx.x; i < n; i += gridDim.x * 256)
        out[i] = f2bf_rne(in[i]);
}

// dec_in[b][t][c]: t==0 -> x_enc[b][191][c], else x_dec[b][t-1][c]
__global__ __launch_bounds__(256) void k_build_decin(const float* __restrict__ x_enc,
                                                     const float* __restrict__ x_dec,
                                                     short* __restrict__ out) {
    int i = blockIdx.x * 256 + threadIdx.x;
    if (i >= BB * TDEC * 32) return;
    int c = i & 31;
    int t = (i >> 5) % TDEC;
    int b = i / (TDEC * 32);
    float v = (t == 0) ? x_enc[(size_t)b * TENC * 32 + 191 * 32 + c]
                       : x_dec[(size_t)b * TDEC * 32 + (t - 1) * 32 + c];
    out[i] = f2bf_rne(v);
}

// ---- partial-K matmul bodies (one wave = 16(b) x 16(i), 3 gates) ----
__device__ __forceinline__ void big_partial(
    int b0, int i0, int kh, int lane,
    const short* __restrict__ ybf, const short* __restrict__ wih,
    const short* __restrict__ whh, const short* __restrict__ hbf_old,
    f32x4& accR, f32x4& accZ, f32x4& accGN, f32x4& accHN)
{
    const int lr = lane & 15;
    const int kg = lane >> 4;
    const int k0 = kh * 512;
    const short* ay  = ybf     + (size_t)(b0 + lr) * H + k0 + kg * 8;
    const short* ah  = hbf_old + (size_t)(b0 + lr) * H + k0 + kg * 8;
    const short* wir = wih + (size_t)(i0 + lr) * H + k0 + kg * 8;
    const short* wiz = wir + (size_t)H * H;
    const short* win = wir + (size_t)(2 * H) * H;
    const short* whr = whh + (size_t)(i0 + lr) * H + k0 + kg * 8;
    const short* whz = whr + (size_t)H * H;
    const short* whn = whr + (size_t)(2 * H) * H;
    #pragma unroll 2
    for (int kk = 0; kk < 512; kk += 32) {
        bf16x8 vy  = *(const bf16x8*)(ay + kk);
        bf16x8 vh  = *(const bf16x8*)(ah + kk);
        bf16x8 vir = *(const bf16x8*)(wir + kk);
        bf16x8 viz = *(const bf16x8*)(wiz + kk);
        bf16x8 vin = *(const bf16x8*)(win + kk);
        bf16x8 vhr = *(const bf16x8*)(whr + kk);
        bf16x8 vhz = *(const bf16x8*)(whz + kk);
        bf16x8 vhn = *(const bf16x8*)(whn + kk);
        accR  = __builtin_amdgcn_mfma_f32_16x16x32_bf16(vy, vir, accR, 0, 0, 0);
        accR  = __builtin_amdgcn_mfma_f32_16x16x32_bf16(vh, vhr, accR, 0, 0, 0);
        accZ  = __builtin_amdgcn_mfma_f32_16x16x32_bf16(vy, viz, accZ, 0, 0, 0);
        accZ  = __builtin_amdgcn_mfma_f32_16x16x32_bf16(vh, vhz, accZ, 0, 0, 0);
        accGN = __builtin_amdgcn_mfma_f32_16x16x32_bf16(vy, vin, accGN, 0, 0, 0);
        accHN = __builtin_amdgcn_mfma_f32_16x16x32_bf16(vh, vhn, accHN, 0, 0, 0);
    }
}

__device__ __forceinline__ void small_partial(
    int b0, int i0, int kh, int lane,
    const short* __restrict__ xbf, int xstride, int xoff,
    const short* __restrict__ wih, const short* __restrict__ whh,
    const short* __restrict__ hbf_old,
    f32x4& accR, f32x4& accZ, f32x4& accGN, f32x4& accHN)
{
    const int lr = lane & 15;
    const int kg = lane >> 4;
    const int k0 = kh * 512;
    const short* ar = hbf_old + (size_t)(b0 + lr) * H + k0 + kg * 8;
    const short* wr = whh + (size_t)(i0 + lr) * H + k0 + kg * 8;
    const short* wz = wr + (size_t)H * H;
    const short* wn = wr + (size_t)(2 * H) * H;
    #pragma unroll 2
    for (int kk = 0; kk < 512; kk += 32) {
        bf16x8 a  = *(const bf16x8*)(ar + kk);
        bf16x8 br = *(const bf16x8*)(wr + kk);
        bf16x8 bz = *(const bf16x8*)(wz + kk);
        bf16x8 bn = *(const bf16x8*)(wn + kk);
        accR  = __builtin_amdgcn_mfma_f32_16x16x32_bf16(a, br, accR, 0, 0, 0);
        accZ  = __builtin_amdgcn_mfma_f32_16x16x32_bf16(a, bz, accZ, 0, 0, 0);
        accHN = __builtin_amdgcn_mfma_f32_16x16x32_bf16(a, bn, accHN, 0, 0, 0);
    }
    if (kh == 0) {   // gi: K=32 input matmul, single MFMA chunk per gate
        bf16x8 a  = *(const bf16x8*)(xbf + (size_t)(b0 + lr) * xstride + xoff + kg * 8);
        bf16x8 br = *(const bf16x8*)(wih + (size_t)(i0 + lr) * 32 + kg * 8);
        bf16x8 bz = *(const bf16x8*)(wih + (size_t)(H + i0 + lr) * 32 + kg * 8);
        bf16x8 bn = *(const bf16x8*)(wih + (size_t)(2 * H + i0 + lr) * 32 + kg * 8);
        accR  = __builtin_amdgcn_mfma_f32_16x16x32_bf16(a, br, accR, 0, 0, 0);
        accZ  = __builtin_amdgcn_mfma_f32_16x16x32_bf16(a, bz, accZ, 0, 0, 0);
        accGN = __builtin_amdgcn_mfma_f32_16x16x32_bf16(a, bn, accGN, 0, 0, 0);
    }
}

// Persistent kernel: all 290 diagonal steps with internal grid barrier.
__global__ __launch_bounds__(1024) void k_persist(
    const short* __restrict__ xencbf, const short* __restrict__ decinbf,
    const short* __restrict__ wih0e, const short* __restrict__ whh0e,
    const float* __restrict__ ebih0, const float* __restrict__ ebhh0,
    const short* __restrict__ wih1e, const short* __restrict__ whh1e,
    const float* __restrict__ ebih1, const float* __restrict__ ebhh1,
    const short* __restrict__ wih0d, const short* __restrict__ whh0d,
    const float* __restrict__ dbih0, const float* __restrict__ dbhh0,
    const short* __restrict__ wih1d, const short* __restrict__ whh1d,
    const float* __restrict__ dbih1, const float* __restrict__ dbhh1,
    short* __restrict__ y0r, float* __restrict__ pp0,
    short* __restrict__ hbf1, float* __restrict__ pp1,
    float* __restrict__ y1, unsigned* __restrict__ ctr)
{
    __shared__ float red[8][4][256];   // [team][acc][reg*64+lane]
    const int tid  = threadIdx.x;
    const int team = tid >> 7;          // 0..7 (2 waves each)
    const int kh   = (tid >> 6) & 1;    // K-half
    const int lane = tid & 63;
    const int lr = lane & 15;
    const int kg = lane >> 4;
    const int bid = blockIdx.x;
    const size_t HS = (size_t)BB * H;

    for (int u = 0; u < NSTEP; ++u) {
        // ---- uniform step parameters ----
        const bool enc = (u < TENC + 1);
        const int s = enc ? u : (u - (TENC + 1));
        const short* x       = enc ? xencbf : decinbf;
        const int    xstride = enc ? TENC * 32 : TDEC * 32;
        const short* wih0 = enc ? wih0e : wih0d;
        const short* whh0 = enc ? whh0e : whh0d;
        const short* wih1 = enc ? wih1e : wih1d;
        const short* whh1 = enc ? whh1e : whh1d;
        const float* bih0 = enc ? ebih0 : dbih0;
        const float* bhh0 = enc ? ebhh0 : dbhh0;
        const float* bih1 = enc ? ebih1 : dbih1;
        const float* bhh1 = enc ? ebhh1 : dbhh1;
        const int act0 = enc ? (s < TENC) : (s < TDEC);
        const int act1 = (s >= 1);

        const short* h0b_old = y0r + (size_t)(s & 1) * HS;
        short*       h0b_new = y0r + (size_t)((s + 1) & 1) * HS;
        const float* h0f_old = pp0 + (size_t)(s & 1) * HS;
        float*       h0f_new = pp0 + (size_t)((s + 1) & 1) * HS;
        const short* y0in    = h0b_old;
        const short* h1b_old = hbf1 + (size_t)((s - 1) & 1) * HS;
        short*       h1b_new = hbf1 + (size_t)(s & 1) * HS;
        const float* h1f_old;
        float*       h1f_new;
        if (enc) {
            h1f_old = pp1 + (size_t)((s - 1) & 1) * HS;
            h1f_new = pp1 + (size_t)(s & 1) * HS;
        } else {
            h1f_old = (s == 1) ? pp1 : (y1 + (size_t)(s - 2) * HS);
            h1f_new = (s >= 1) ? (y1 + (size_t)(s - 1) * HS) : pp1;
        }

        // ---- tile task for this team ----
        const int tau = bid + NBLK * team;       // 0..1791; <1024 are real
        const bool isbig = (tau < 512);
        const int tt = isbig ? tau : (tau - 512);
        const int b0 = (tt >> 6) * 16;
        const int i0 = (tt & 63) * 16;
        const bool active = (tau < 1024) && (isbig ? (act1 != 0) : (act0 != 0));

        f32x4 accR = {0.f, 0.f, 0.f, 0.f};
        f32x4 accZ = accR, accGN = accR, accHN = accR;
        if (active) {
            if (isbig)
                big_partial(b0, i0, kh, lane, y0in, wih1, whh1, h1b_old,
                            accR, accZ, accGN, accHN);
            else
                small_partial(b0, i0, kh, lane, x, xstride, s * 32,
                              wih0, whh0, h0b_old, accR, accZ, accGN, accHN);
        }
        if (active && kh == 1) {
            #pragma unroll
            for (int r = 0; r < 4; ++r) {
                red[team][0][r * 64 + lane] = accR[r];
                red[team][1][r * 64 + lane] = accZ[r];
                red[team][2][r * 64 + lane] = accGN[r];
                red[team][3][r * 64 + lane] = accHN[r];
            }
        }
        __syncthreads();
        if (active && kh == 0) {
            #pragma unroll
            for (int r = 0; r < 4; ++r) {
                accR[r]  += red[team][0][r * 64 + lane];
                accZ[r]  += red[team][1][r * 64 + lane];
                accGN[r] += red[team][2][r * 64 + lane];
                accHN[r] += red[team][3][r * 64 + lane];
            }
            const float* bih = isbig ? bih1 : bih0;
            const float* bhh = isbig ? bhh1 : bhh0;
            const float* hfo = isbig ? h1f_old : h0f_old;
            float*       hfn = isbig ? h1f_new : h0f_new;
            short*       hbn = isbig ? h1b_new : h0b_new;
            const int col = i0 + lr;
            const float bR  = bih[col] + bhh[col];
            const float bZ  = bih[H + col] + bhh[H + col];
            const float bGN = bih[2 * H + col];
            const float bHN = bhh[2 * H + col];
            #pragma unroll
            for (int r = 0; r < 4; ++r) {
                int row = b0 + kg * 4 + r;
                float vr = sigmoidf_(accR[r] + bR);
                float vz = sigmoidf_(accZ[r] + bZ);
                float vn = tanhf(accGN[r] + bGN + vr * (accHN[r] + bHN));
                float ho = hfo[(size_t)row * H + col];
                float hn = (1.0f - vz) * vn + vz * ho;
                hfn[(size_t)row * H + col] = hn;
                hbn[(size_t)row * H + col] = f2bf_rne(hn);
            }
        }
        // ---- device-wide barrier (monotonic, 16 striped counters) ----
        __syncthreads();   // all block stores issued (s_barrier drains vmcnt)
        if (tid == 0) {
            __threadfence();   // release: write back this XCD's L2
            __hip_atomic_fetch_add(&ctr[(bid & 15) * 32], 1u,
                                   __ATOMIC_RELAXED, __HIP_MEMORY_SCOPE_AGENT);
            const unsigned tgt = (unsigned)(u + 1) * NBLK;
            for (;;) {
                unsigned ssum = 0;
                #pragma unroll
                for (int i = 0; i < 16; ++i)
                    ssum += __hip_atomic_load(&ctr[i * 32], __ATOMIC_RELAXED,
                                              __HIP_MEMORY_SCOPE_AGENT);
                if (ssum >= tgt) break;
                __builtin_amdgcn_s_sleep(4);
            }
            __threadfence();   // acquire: invalidate stale lines
        }
        __syncthreads();
    }
}

// out[b][t][o] = sum_h y1[t][b][h] * W[o][h] + bias[o]   (pure fp32)
__global__ __launch_bounds__(256) void k_proj(const float* __restrict__ y1,
                                              const float* __restrict__ W,
                                              const float* __restrict__ bias,
                                              float* __restrict__ out) {
    int idx = blockIdx.x * 256 + threadIdx.x;
    if (idx >= TDEC * BB * 32) return;
    int o = idx & 31;
    int rt = idx >> 5;        // t*BB + b
    int t = rt >> 7;
    int b = rt & (BB - 1);
    const float4* yr = (const float4*)(y1 + (size_t)rt * H);
    const float4* wr = (const float4*)(W + (size_t)o * H);
    float s = 0.f;
    #pragma unroll 4
    for (int k = 0; k < H / 4; ++k) {
        float4 a = yr[k], w = wr[k];
        s += a.x * w.x + a.y * w.y + a.z * w.z + a.w * w.w;
    }
    out[(size_t)b * TDEC * 32 + (size_t)t * 32 + o] = s + bias[o];
}

extern "C" void kernel_launch(void* const* d_in, const int* in_sizes, int n_in,
                              void* d_out, int out_size, void* d_ws, size_t ws_size,
                              hipStream_t stream) {
    const float* x_enc = (const float*)d_in[0];
    const float* x_dec = (const float*)d_in[2];
    const float* eWih0 = (const float*)d_in[4];
    const float* eWhh0 = (const float*)d_in[5];
    const float* ebih0 = (const float*)d_in[6];
    const float* ebhh0 = (const float*)d_in[7];
    const float* eWih1 = (const float*)d_in[8];
    const float* eWhh1 = (const float*)d_in[9];
    const float* ebih1 = (const float*)d_in[10];
    const float* ebhh1 = (const float*)d_in[11];
    const float* dWih0 = (const float*)d_in[12];
    const float* dWhh0 = (const float*)d_in[13];
    const float* dbih0 = (const float*)d_in[14];
    const float* dbhh0 = (const float*)d_in[15];
    const float* dWih1 = (const float*)d_in[16];
    const float* dWhh1 = (const float*)d_in[17];
    const float* dbih1 = (const float*)d_in[18];
    const float* dbhh1 = (const float*)d_in[19];
    const float* outW  = (const float*)d_in[20];
    const float* outb  = (const float*)d_in[21];
    float* out = (float*)d_out;

    char* ws = (char*)d_ws;
    size_t off = 0;
    auto alloc = [&](size_t bytes) -> void* {
        void* p = ws + off;
        off += (bytes + 255) & ~(size_t)255;
        return p;
    };
    const size_t HS = (size_t)BB * H;
    short* wih0e  = (short*)alloc((size_t)G * 32 * 2);
    short* whh0e  = (short*)alloc((size_t)G * H * 2);
    short* wih1e  = (short*)alloc((size_t)G * H * 2);
    short* whh1e  = (short*)alloc((size_t)G * H * 2);
    short* wih0d  = (short*)alloc((size_t)G * 32 * 2);
    short* whh0d  = (short*)alloc((size_t)G * H * 2);
    short* wih1d  = (short*)alloc((size_t)G * H * 2);
    short* whh1d  = (short*)alloc((size_t)G * H * 2);
    short* xencbf = (short*)alloc((size_t)BB * TENC * 32 * 2);
    short* decinbf= (short*)alloc((size_t)BB * TDEC * 32 * 2);
    short* y0r    = (short*)alloc(2 * HS * 2);
    float* pp0    = (float*)alloc(2 * HS * 4);
    short* hbf1   = (short*)alloc(2 * HS * 2);
    float* pp1    = (float*)alloc(2 * HS * 4);
    float* y1     = (float*)alloc((size_t)TDEC * HS * 4);
    unsigned* ctr = (unsigned*)alloc(16 * 32 * 4);
    (void)ws_size; (void)in_sizes; (void)n_in; (void)out_size;

    hipMemsetAsync(y0r, 0, HS * 2, stream);
    hipMemsetAsync(pp0, 0, HS * 4, stream);
    hipMemsetAsync(hbf1, 0, HS * 2, stream);
    hipMemsetAsync(pp1, 0, HS * 4, stream);
    hipMemsetAsync(ctr, 0, 16 * 32 * 4, stream);

    auto cvt = [&](const float* src, short* dst, int n) {
        int blocks = (n + 255) / 256;
        if (blocks > 2048) blocks = 2048;
        k_f2bf<<<dim3(blocks), dim3(256), 0, stream>>>(src, dst, n);
    };
    cvt(eWih0, wih0e, G * 32);
    cvt(eWhh0, whh0e, G * H);
    cvt(eWih1, wih1e, G * H);
    cvt(eWhh1, whh1e, G * H);
    cvt(dWih0, wih0d, G * 32);
    cvt(dWhh0, whh0d, G * H);
    cvt(dWih1, wih1d, G * H);
    cvt(dWhh1, whh1d, G * H);
    cvt(x_enc, xencbf, BB * TENC * 32);
    k_build_decin<<<dim3((BB * TDEC * 32 + 255) / 256), dim3(256), 0, stream>>>(
        x_enc, x_dec, decinbf);

    k_persist<<<dim3(NBLK), dim3(1024), 0, stream>>>(
        xencbf, decinbf,
        wih0e, whh0e, ebih0, ebhh0, wih1e, whh1e, ebih1, ebhh1,
        wih0d, whh0d, dbih0, dbhh0, wih1d, whh1d, dbih1, dbhh1,
        y0r, pp0, hbf1, pp1, y1, ctr);

    k_proj<<<dim3((TDEC * BB * 32 + 255) / 256), dim3(256), 0, stream>>>(
        y1, outW, outb, out);
}